// Round 11
// baseline (91.305 us; speedup 1.0000x reference)
//
#include <hip/hip_runtime.h>
#include <hip/hip_bf16.h>
#include <cstdint>

typedef float f32x4 __attribute__((ext_vector_type(4)));
typedef float f32x16 __attribute__((ext_vector_type(16)));
typedef short s16x8 __attribute__((ext_vector_type(8)));
typedef short s16x4 __attribute__((ext_vector_type(4)));
typedef unsigned int u32x2 __attribute__((ext_vector_type(2)));
typedef unsigned int u32x4 __attribute__((ext_vector_type(4)));

constexpr int B_ = 2, L_ = 2048, D_ = 1024, H_ = 16, DH = 64, HALF = 64;
constexpr int M_ROWS = B_ * L_;   // 4096
constexpr int QKV_N = 3 * D_;     // 3072

__device__ __forceinline__ void gload16(const void* g, void* l) {
    __builtin_amdgcn_global_load_lds(
        (const __attribute__((address_space(1))) unsigned int*)g,
        (__attribute__((address_space(3))) unsigned int*)l, 16, 0, 0);
}

__device__ __forceinline__ void cfence() {
    __builtin_amdgcn_sched_barrier(0);
    asm volatile("" ::: "memory");
}

// ---------------- fused prep: weight cvt (blocks 0..4095) + RMSNorm (4096..5119) ----------------
__global__ __launch_bounds__(256) void prep_kernel(const float* __restrict__ x,
                                                   const float* __restrict__ wn,
                                                   const float* __restrict__ wq,
                                                   const float* __restrict__ wo,
                                                   __hip_bfloat16* __restrict__ xn,
                                                   __hip_bfloat16* __restrict__ oq,
                                                   __hip_bfloat16* __restrict__ oo) {
    constexpr int NQ4 = QKV_N * D_ / 4;              // 786432
    constexpr int NCVT = NQ4 + D_ * D_ / 4;          // 1048576
    constexpr int CVTBLK = NCVT / 256;               // 4096
    int bid = blockIdx.x;
    if (bid < CVTBLK) {
        int i = bid * 256 + threadIdx.x;
        const float* src; __hip_bfloat16* dst; int j;
        if (i < NQ4) { src = wq; dst = oq; j = i; }
        else         { src = wo; dst = oo; j = i - NQ4; }
        float4 v = reinterpret_cast<const float4*>(src)[j];
        s16x4 pk;
        float vals[4] = {v.x, v.y, v.z, v.w};
#pragma unroll
        for (int e = 0; e < 4; ++e) {
            __hip_bfloat16 t = __float2bfloat16(vals[e]);
            pk[e] = *reinterpret_cast<short*>(&t);
        }
        *(s16x4*)(dst + (size_t)j * 4) = pk;
    } else {
        int w = threadIdx.x >> 6, lane = threadIdx.x & 63;
        int row = (bid - CVTBLK) * 4 + w;
        const float4* xr = reinterpret_cast<const float4*>(x + (size_t)row * D_);
        const float4* wr = reinterpret_cast<const float4*>(wn);
        float4 v[4];
        float ss = 0.f;
#pragma unroll
        for (int c = 0; c < 4; ++c) {
            v[c] = xr[c * 64 + lane];
            ss += v[c].x * v[c].x + v[c].y * v[c].y + v[c].z * v[c].z + v[c].w * v[c].w;
        }
#pragma unroll
        for (int off = 32; off; off >>= 1) ss += __shfl_xor(ss, off);
        float rinv = rsqrtf(ss * (1.0f / D_) + 1e-6f);
#pragma unroll
        for (int c = 0; c < 4; ++c) {
            float4 wv = wr[c * 64 + lane];
            s16x4 pk;
            float vals[4] = {v[c].x * rinv * wv.x, v[c].y * rinv * wv.y,
                             v[c].z * rinv * wv.z, v[c].w * rinv * wv.w};
#pragma unroll
            for (int e = 0; e < 4; ++e) {
                __hip_bfloat16 t = __float2bfloat16(vals[e]);
                pk[e] = *reinterpret_cast<short*>(&t);
            }
            *(s16x4*)(xn + (size_t)row * D_ + (c * 64 + lane) * 4) = pk;
        }
    }
}

// ---------------- QKV GEMM: 256x256 tile, 8 waves, cross-iteration frag prefetch ----------------
// BK=32, 4 LDS buffers (128 KB). Epoch t (between barrier t and t+1):
//   [vmcnt(4)+s_barrier fused: own tile-(t+1) loads certified, then published]
//   -> cfence -> STAGE(t+3) -> ds_read B(t) [4] -> ds_read A(t+1) [8, overlaps MFMA]
//   -> 32 MFMA on A(t) [read last epoch] x B(t).
// Buffer map in epoch t: write (t+3)&3==(t-1)&3, read t&3 and (t+1)&3 - all distinct mod 4;
// STAGE is after the barrier, so B(t-1) readers are barrier-separated from the overwrite.
__global__ __launch_bounds__(512, 2) void gemm_qkv_kernel(const __hip_bfloat16* __restrict__ A,
                                                          const __hip_bfloat16* __restrict__ Bt,
                                                          __hip_bfloat16* __restrict__ Cbf,
                                                          __hip_bfloat16* __restrict__ vT,
                                                          int M, int N, int K) {
    constexpr int ATILE = 16384;               // 256 rows x 64 B
    constexpr int BUFB = 32768;                // A + B per K-tile
    constexpr int NT = 32;                     // K=1024 / BK=32
    __shared__ __align__(16) char smem[4 * BUFB];   // 128 KB

    const int tid = threadIdx.x;
    const int lane = tid & 63;
    const int wid = tid >> 6;

    // XCD-aware bijective swizzle (nwg = 192, % 8 == 0)
    int nwg = gridDim.x * gridDim.y;
    int lin = blockIdx.y * gridDim.x + blockIdx.x;
    int cpx = nwg >> 3;
    int swz = (lin & 7) * cpx + (lin >> 3);
    int bx = swz % gridDim.x;
    int by = swz / gridDim.x;

    const int rowBase = by * 256;
    const int colBase = bx * 256;

    // staging coords: thread covers rows r0 (+128 on 2nd issue), slot tid&3
    const int r0 = tid >> 2;                   // 0..127
    const int cA = ((tid & 3) ^ ((r0 ^ (r0 >> 2)) & 3)) << 3;   // inverse-swizzled col
    const __hip_bfloat16* aG = A + (size_t)(rowBase + r0) * K + cA;
    const __hip_bfloat16* bG = Bt + (size_t)(colBase + r0) * K + cA;
    const int dstW = wid << 10;                // wave-uniform; HW adds lane*16

    // fragment read coords
    const int wm = wid >> 2, wn = wid & 3;     // 2 x 4 waves
    const int l15 = lane & 15, hi = lane >> 4;
    const int swzl = (l15 ^ (l15 >> 2)) & 3;
    const int aRd = wm * 8192 + l15 * 64 + ((hi ^ swzl) << 4);         // + mf*1024
    const int bRd = ATILE + wn * 4096 + l15 * 64 + ((hi ^ swzl) << 4); // + nf*1024

    f32x4 acc[8][4];
#pragma unroll
    for (int m = 0; m < 8; ++m)
#pragma unroll
        for (int n = 0; n < 4; ++n) acc[m][n] = (f32x4){0.f, 0.f, 0.f, 0.f};

    auto STAGE = [&](int tt) {
        char* base = smem + (tt & 3) * BUFB + dstW;
        const __hip_bfloat16* as = aG + (size_t)tt * 32;
        const __hip_bfloat16* bs = bG + (size_t)tt * 32;
        gload16(as, base);
        gload16(as + (size_t)128 * K, base + 8192);
        gload16(bs, base + ATILE);
        gload16(bs + (size_t)128 * K, base + ATILE + 8192);
    };

    STAGE(0);
    STAGE(1);
    STAGE(2);
    // certify tiles 0 AND 1 (12 outstanding -> leave tile 2's 4), publish
    asm volatile("s_waitcnt vmcnt(4)\n\ts_barrier" ::: "memory");
    cfence();

    s16x8 aA[8], aB[8], bc[4];
#pragma unroll
    for (int mf = 0; mf < 8; ++mf)
        aA[mf] = *(const s16x8*)(smem + aRd + mf * 1024);   // A(0) from buf0

    auto body = [&](int t, s16x8 (&cur)[8], s16x8 (&nxt)[8]) {
        if (t + 1 < NT) {
            if (t + 2 < NT)
                asm volatile("s_waitcnt vmcnt(4)\n\ts_barrier" ::: "memory");
            else
                asm volatile("s_waitcnt vmcnt(0)\n\ts_barrier" ::: "memory");
            cfence();
        }
        if (t + 3 < NT) STAGE(t + 3);
        const char* tb = smem + (t & 3) * BUFB;
#pragma unroll
        for (int nf = 0; nf < 4; ++nf)
            bc[nf] = *(const s16x8*)(tb + bRd + nf * 1024);
        if (t + 1 < NT) {
            const char* nb = smem + ((t + 1) & 3) * BUFB;
#pragma unroll
            for (int mf = 0; mf < 8; ++mf)
                nxt[mf] = *(const s16x8*)(nb + aRd + mf * 1024);   // overlaps MFMA below
        }
        __builtin_amdgcn_s_setprio(1);
#pragma unroll
        for (int mf = 0; mf < 8; ++mf)
#pragma unroll
            for (int nf = 0; nf < 4; ++nf)
                acc[mf][nf] = __builtin_amdgcn_mfma_f32_16x16x32_bf16(cur[mf], bc[nf],
                                                                      acc[mf][nf], 0, 0, 0);
        __builtin_amdgcn_s_setprio(0);
    };

    for (int tt = 0; tt < NT; tt += 2) {
        body(tt, aA, aB);
        body(tt + 1, aB, aA);
    }

    if (colBase < 2 * D_) {                     // q,k section: direct stores
#pragma unroll
        for (int mf = 0; mf < 8; ++mf)
#pragma unroll
            for (int nf = 0; nf < 4; ++nf) {
                int col = colBase + wn * 64 + nf * 16 + l15;
                int row0 = rowBase + wm * 128 + mf * 16 + 4 * hi;
#pragma unroll
                for (int r = 0; r < 4; ++r)
                    Cbf[(size_t)(row0 + r) * N + col] = __float2bfloat16(acc[mf][nf][r]);
            }
    } else {                                    // v section: 2-pass LDS transpose -> vT
        __syncthreads();                        // all waves done with LDS main loop
        int bb2 = rowBase >> 11, i0 = rowBase & (L_ - 1);
#pragma unroll
        for (int p = 0; p < 2; ++p) {
            if (p) __syncthreads();             // pass-0 reads done before overwrite
            if ((wn >> 1) == p) {
#pragma unroll
                for (int mf = 0; mf < 8; ++mf)
#pragma unroll
                    for (int nf = 0; nf < 4; ++nf) {
                        int clp = (wn & 1) * 64 + nf * 16 + l15;
                        int rlb = wm * 128 + mf * 16 + 4 * hi;
                        s16x4 pk;
#pragma unroll
                        for (int r = 0; r < 4; ++r) {
                            __hip_bfloat16 t = __float2bfloat16(acc[mf][nf][r]);
                            pk[r] = *reinterpret_cast<short*>(&t);
                        }
                        *(s16x4*)(smem + clp * 528 + rlb * 2) = pk;
                    }
            }
            __syncthreads();
            {
                int c = tid >> 2, qd = tid & 3;
                int gcol = colBase + p * 128 + c - 2 * D_;
                int hh = gcol >> 6, dd = gcol & 63;
                __hip_bfloat16* dstp = vT + ((size_t)(bb2 * H_ + hh) * DH + dd) * L_ + i0 + qd * 64;
#pragma unroll
                for (int ch = 0; ch < 8; ++ch)
                    *(s16x8*)(dstp + ch * 8) = *(const s16x8*)(smem + c * 528 + qd * 128 + ch * 16);
            }
        }
    }
}

// ---------------- out-proj GEMM (round-9 proven): 128 x 64 tile, BK=32, 4 buffers ----------------
__global__ __launch_bounds__(256, 3) void gemm_proj_kernel(const __hip_bfloat16* __restrict__ A,
                                                           const __hip_bfloat16* __restrict__ Bt,
                                                           float* __restrict__ Cf,
                                                           const float* __restrict__ resid,
                                                           int M, int N, int K) {
    constexpr int BM = 128, BN = 64;
    constexpr int ATILE = BM * 64;             // 8192
    constexpr int BTILE = BN * 64;             // 4096
    constexpr int BUFB = ATILE + BTILE;        // 12288
    __shared__ __align__(16) char smem[4 * BUFB];   // 48 KB

    const int tid = threadIdx.x;
    const int lane = tid & 63;
    const int wid = tid >> 6;

    int nwg = gridDim.x * gridDim.y;
    int lin = blockIdx.y * gridDim.x + blockIdx.x;
    int cpx = nwg >> 3;
    int swz = (lin & 7) * cpx + (lin >> 3);
    int bx = swz % gridDim.x;
    int by = swz / gridDim.x;

    const int rowBase = by * BM;
    const int colBase = bx * BN;
    const int NT = K >> 5;

    const int r0 = tid >> 2;                   // 0..63
    const int cS = ((tid & 3) ^ ((r0 ^ (r0 >> 2)) & 3)) << 3;
    const __hip_bfloat16* aG = A + (size_t)(rowBase + r0) * K + cS;
    const __hip_bfloat16* bG = Bt + (size_t)(colBase + r0) * K + cS;
    const int dstW = wid << 10;

    const int wm = wid >> 1, wn = wid & 1;
    const int l15 = lane & 15, hi = lane >> 4;
    const int swzl = (l15 ^ (l15 >> 2)) & 3;
    const int aRd = wm * 4096 + l15 * 64 + ((hi ^ swzl) << 4);
    const int bRd = ATILE + wn * 2048 + l15 * 64 + ((hi ^ swzl) << 4);

    f32x4 acc[4][2];
#pragma unroll
    for (int m = 0; m < 4; ++m)
#pragma unroll
        for (int n = 0; n < 2; ++n) acc[m][n] = (f32x4){0.f, 0.f, 0.f, 0.f};

    auto STAGE = [&](int tt) {
        char* base = smem + (tt & 3) * BUFB + dstW;
        const __hip_bfloat16* as = aG + (size_t)tt * 32;
        const __hip_bfloat16* bs = bG + (size_t)tt * 32;
        gload16(as, base);
        gload16(as + (size_t)64 * K, base + 4096);
        gload16(bs, base + ATILE);
    };

    STAGE(0);
    STAGE(1);

    for (int t = 0; t < NT; ++t) {
        if (t + 2 < NT) {
            STAGE(t + 2);
            asm volatile("s_waitcnt vmcnt(6)" ::: "memory");
        } else if (t + 1 < NT) {
            asm volatile("s_waitcnt vmcnt(3)" ::: "memory");
        } else {
            asm volatile("s_waitcnt vmcnt(0)" ::: "memory");
        }
        asm volatile("s_waitcnt lgkmcnt(0)" ::: "memory");
        __builtin_amdgcn_s_barrier();
        cfence();

        const char* tb = smem + (t & 3) * BUFB;
        s16x8 af[4], bf[2];
#pragma unroll
        for (int mf = 0; mf < 4; ++mf)
            af[mf] = *(const s16x8*)(tb + aRd + mf * 1024);
#pragma unroll
        for (int nf = 0; nf < 2; ++nf)
            bf[nf] = *(const s16x8*)(tb + bRd + nf * 1024);

        __builtin_amdgcn_s_setprio(1);
#pragma unroll
        for (int mf = 0; mf < 4; ++mf)
#pragma unroll
            for (int nf = 0; nf < 2; ++nf)
                acc[mf][nf] = __builtin_amdgcn_mfma_f32_16x16x32_bf16(af[mf], bf[nf],
                                                                      acc[mf][nf], 0, 0, 0);
        __builtin_amdgcn_s_setprio(0);
    }

#pragma unroll
    for (int mf = 0; mf < 4; ++mf)
#pragma unroll
        for (int nf = 0; nf < 2; ++nf) {
            int col = colBase + wn * 32 + nf * 16 + l15;
            int row0 = rowBase + wm * 64 + mf * 16 + 4 * hi;
#pragma unroll
            for (int r = 0; r < 4; ++r)
                Cf[(size_t)(row0 + r) * N + col] = acc[mf][nf][r] + resid[(size_t)(row0 + r) * N + col];
        }
}

// ---------------- barrier-free LDS-free MFMA banded attention (round-8, proven) ----------------
__global__ __launch_bounds__(128, 2) void attn_mfma_kernel(const __hip_bfloat16* __restrict__ qkv,
                                                           const __hip_bfloat16* __restrict__ vT,
                                                           __hip_bfloat16* __restrict__ attn) {
    int tid = threadIdx.x;
    int w = tid >> 6;
    int lane = tid & 63;
    int l31 = lane & 31, hi1 = lane >> 5;
    int tq = blockIdx.x, h = blockIdx.y, b = blockIdx.z;
    int qbase = tq * 64 + 32 * w;
    int kb = qbase - HALF;
    int qg = qbase + l31;
    const __hip_bfloat16* qkvb = qkv + (size_t)(b * L_) * QKV_N;
    const __hip_bfloat16* vTg = vT + (size_t)(b * H_ + h) * DH * L_;

    s16x8 qf[4];
#pragma unroll
    for (int kk = 0; kk < 4; ++kk)
        qf[kk] = *(const s16x8*)(qkvb + (size_t)qg * QKV_N + h * DH + kk * 16 + hi1 * 8);

    f32x16 T[5];
#pragma unroll
    for (int kt = 0; kt < 5; ++kt) T[kt] = (f32x16)(0.f);
#pragma unroll
    for (int kt = 0; kt < 5; ++kt) {
        int keyg = kb + 32 * kt + l31;
        int kc = keyg < 0 ? 0 : (keyg > L_ - 1 ? L_ - 1 : keyg);
        const __hip_bfloat16* kp = qkvb + (size_t)kc * QKV_N + D_ + h * DH + hi1 * 8;
#pragma unroll
        for (int kk = 0; kk < 4; ++kk) {
            s16x8 kf = *(const s16x8*)(kp + kk * 16);
            T[kt] = __builtin_amdgcn_mfma_f32_32x32x16_bf16(kf, qf[kk], T[kt], 0, 0, 0);
        }
    }

    float mx = -1e30f;
#pragma unroll
    for (int kt = 0; kt < 5; ++kt) {
#pragma unroll
        for (int r = 0; r < 16; ++r) {
            int koff = (r & 3) + 8 * (r >> 2) + 4 * hi1;
            int keyg = kb + 32 * kt + koff;
            int del = keyg - qg;
            bool ok = (del >= -HALF) && (del <= HALF) && (keyg >= 0) && (keyg < L_);
            float t = ok ? T[kt][r] * 0.125f : -1e30f;
            T[kt][r] = t;
            mx = fmaxf(mx, t);
        }
    }
    mx = fmaxf(mx, __shfl_xor(mx, 32));
    float sum = 0.f;
#pragma unroll
    for (int kt = 0; kt < 5; ++kt) {
#pragma unroll
        for (int r = 0; r < 16; ++r) {
            float p = __expf(T[kt][r] - mx);
            T[kt][r] = p;
            sum += p;
        }
    }
    sum += __shfl_xor(sum, 32);
    float inv = 1.0f / sum;

    u32x4 pu[10];
#pragma unroll
    for (int kt = 0; kt < 5; ++kt) {
#pragma unroll
        for (int s = 0; s < 2; ++s) {
            unsigned P0, P1, P2, P3;
            asm("v_cvt_pk_bf16_f32 %0, %1, %2" : "=v"(P0) : "v"(T[kt][8 * s + 0]), "v"(T[kt][8 * s + 1]));
            asm("v_cvt_pk_bf16_f32 %0, %1, %2" : "=v"(P1) : "v"(T[kt][8 * s + 2]), "v"(T[kt][8 * s + 3]));
            asm("v_cvt_pk_bf16_f32 %0, %1, %2" : "=v"(P2) : "v"(T[kt][8 * s + 4]), "v"(T[kt][8 * s + 5]));
            asm("v_cvt_pk_bf16_f32 %0, %1, %2" : "=v"(P3) : "v"(T[kt][8 * s + 6]), "v"(T[kt][8 * s + 7]));
            u32x2 sA = __builtin_amdgcn_permlane32_swap(P0, P2, false, false);
            u32x2 sB = __builtin_amdgcn_permlane32_swap(P1, P3, false, false);
            pu[2 * kt + s] = (u32x4){sA[0], sB[0], sA[1], sB[1]};
        }
    }

    f32x16 O[2];
#pragma unroll
    for (int dt = 0; dt < 2; ++dt) O[dt] = (f32x16)(0.f);
#pragma unroll
    for (int t = 0; t < 10; ++t) {
        int kv = kb + 16 * t + 8 * hi1;
        kv = kv < 0 ? 0 : (kv > L_ - 8 ? L_ - 8 : kv);
        s16x8 pf = __builtin_bit_cast(s16x8, pu[t]);
#pragma unroll
        for (int dt = 0; dt < 2; ++dt) {
            s16x8 vf = *(const s16x8*)(vTg + (size_t)(32 * dt + l31) * L_ + kv);
            O[dt] = __builtin_amdgcn_mfma_f32_32x32x16_bf16(vf, pf, O[dt], 0, 0, 0);
        }
    }

    __hip_bfloat16* ob = attn + (size_t)(b * L_ + qg) * D_ + h * DH;
#pragma unroll
    for (int dt = 0; dt < 2; ++dt) {
#pragma unroll
        for (int rr = 0; rr < 4; ++rr) {
            s16x4 pk4;
#pragma unroll
            for (int j = 0; j < 4; ++j) {
                __hip_bfloat16 tb = __float2bfloat16(O[dt][4 * rr + j] * inv);
                pk4[j] = *reinterpret_cast<short*>(&tb);
            }
            *(s16x4*)(ob + 32 * dt + 8 * rr + 4 * hi1) = pk4;
        }
    }
}

extern "C" void kernel_launch(void* const* d_in, const int* in_sizes, int n_in,
                              void* d_out, int out_size, void* d_ws, size_t ws_size,
                              hipStream_t stream) {
    const float* x      = (const float*)d_in[0];
    const float* w_norm = (const float*)d_in[1];
    const float* w_qkv  = (const float*)d_in[2];
    const float* w_out  = (const float*)d_in[3];

    char* ws = (char*)d_ws;
    __hip_bfloat16* xn   = (__hip_bfloat16*)(ws);                        //  8 MiB
    __hip_bfloat16* wq   = (__hip_bfloat16*)(ws + (8u  << 20));          //  6 MiB
    __hip_bfloat16* wo   = (__hip_bfloat16*)(ws + (14u << 20));          //  2 MiB
    __hip_bfloat16* qkv  = (__hip_bfloat16*)(ws + (16u << 20));          // 24 MiB (q,k used)
    __hip_bfloat16* attn = (__hip_bfloat16*)(ws + (40u << 20));          //  8 MiB
    __hip_bfloat16* vT   = (__hip_bfloat16*)(ws + (48u << 20));          //  8 MiB
    float* out = (float*)d_out;

    // fused weight conversion + RMSNorm
    prep_kernel<<<4096 + M_ROWS / 4, 256, 0, stream>>>(x, w_norm, w_qkv, w_out, xn, wq, wo);

    // QKV GEMM: [4096,1024] x [3072,1024]^T -> q,k bf16 + vT transposed (256^2 tiles)
    gemm_qkv_kernel<<<dim3(QKV_N / 256, M_ROWS / 256), 512, 0, stream>>>(
        xn, wq, qkv, vT, M_ROWS, QKV_N, D_);

    // MFMA banded attention -> bf16 [4096,1024]
    attn_mfma_kernel<<<dim3(L_ / 64, H_, B_), 128, 0, stream>>>(qkv, vT, attn);

    // out proj + residual: [4096,1024] x [1024,1024]^T + x -> f32 d_out
    gemm_proj_kernel<<<dim3(D_ / 64, M_ROWS / 128), 256, 0, stream>>>(
        attn, wo, out, x, M_ROWS, D_, D_);
}

// Round 12
// 89.684 us; speedup vs baseline: 1.0181x; 1.0181x over previous
//
#include <hip/hip_runtime.h>
#include <hip/hip_bf16.h>
#include <cstdint>

typedef float f32x4 __attribute__((ext_vector_type(4)));
typedef float f32x16 __attribute__((ext_vector_type(16)));
typedef short s16x8 __attribute__((ext_vector_type(8)));
typedef short s16x4 __attribute__((ext_vector_type(4)));
typedef unsigned int u32x2 __attribute__((ext_vector_type(2)));
typedef unsigned int u32x4 __attribute__((ext_vector_type(4)));

constexpr int B_ = 2, L_ = 2048, D_ = 1024, H_ = 16, DH = 64, HALF = 64;
constexpr int M_ROWS = B_ * L_;   // 4096
constexpr int QKV_N = 3 * D_;     // 3072

__device__ __forceinline__ void gload16(const void* g, void* l) {
    __builtin_amdgcn_global_load_lds(
        (const __attribute__((address_space(1))) unsigned int*)g,
        (__attribute__((address_space(3))) unsigned int*)l, 16, 0, 0);
}

__device__ __forceinline__ void cfence() {
    __builtin_amdgcn_sched_barrier(0);
    asm volatile("" ::: "memory");
}

__device__ __forceinline__ void phasebar() {
    cfence();
    __builtin_amdgcn_s_barrier();
    cfence();
}

// ---------------- fused prep: weight cvt (blocks 0..4095) + RMSNorm (4096..5119) ----------------
__global__ __launch_bounds__(256) void prep_kernel(const float* __restrict__ x,
                                                   const float* __restrict__ wn,
                                                   const float* __restrict__ wq,
                                                   const float* __restrict__ wo,
                                                   __hip_bfloat16* __restrict__ xn,
                                                   __hip_bfloat16* __restrict__ oq,
                                                   __hip_bfloat16* __restrict__ oo) {
    constexpr int NQ4 = QKV_N * D_ / 4;              // 786432
    constexpr int NCVT = NQ4 + D_ * D_ / 4;          // 1048576
    constexpr int CVTBLK = NCVT / 256;               // 4096
    int bid = blockIdx.x;
    if (bid < CVTBLK) {
        int i = bid * 256 + threadIdx.x;
        const float* src; __hip_bfloat16* dst; int j;
        if (i < NQ4) { src = wq; dst = oq; j = i; }
        else         { src = wo; dst = oo; j = i - NQ4; }
        float4 v = reinterpret_cast<const float4*>(src)[j];
        s16x4 pk;
        float vals[4] = {v.x, v.y, v.z, v.w};
#pragma unroll
        for (int e = 0; e < 4; ++e) {
            __hip_bfloat16 t = __float2bfloat16(vals[e]);
            pk[e] = *reinterpret_cast<short*>(&t);
        }
        *(s16x4*)(dst + (size_t)j * 4) = pk;
    } else {
        int w = threadIdx.x >> 6, lane = threadIdx.x & 63;
        int row = (bid - CVTBLK) * 4 + w;
        const float4* xr = reinterpret_cast<const float4*>(x + (size_t)row * D_);
        const float4* wr = reinterpret_cast<const float4*>(wn);
        float4 v[4];
        float ss = 0.f;
#pragma unroll
        for (int c = 0; c < 4; ++c) {
            v[c] = xr[c * 64 + lane];
            ss += v[c].x * v[c].x + v[c].y * v[c].y + v[c].z * v[c].z + v[c].w * v[c].w;
        }
#pragma unroll
        for (int off = 32; off; off >>= 1) ss += __shfl_xor(ss, off);
        float rinv = rsqrtf(ss * (1.0f / D_) + 1e-6f);
#pragma unroll
        for (int c = 0; c < 4; ++c) {
            float4 wv = wr[c * 64 + lane];
            s16x4 pk;
            float vals[4] = {v[c].x * rinv * wv.x, v[c].y * rinv * wv.y,
                             v[c].z * rinv * wv.z, v[c].w * rinv * wv.w};
#pragma unroll
            for (int e = 0; e < 4; ++e) {
                __hip_bfloat16 t = __float2bfloat16(vals[e]);
                pk[e] = *reinterpret_cast<short*>(&t);
            }
            *(s16x4*)(xn + (size_t)row * D_ + (c * 64 + lane) * 4) = pk;
        }
    }
}

// ---------------- QKV GEMM: 256x256, BK=64, 8 waves, 4-phase/K-tile (m201-style) ----------------
// LDS: 2 buffers x 64 KB (A[256][128B] | B[256][128B]), slot ^= (row&7) swizzle (0-conflict, r5).
// Phase p of tile t: {ds_read quadrant ops; stage 2 gload16 of tile t+1 half; barrier;
//   setprio 16 MFMA; barrier}.  vmcnt(0) only at phase 4 (certifies t+1 before its P1 reads).
// Per-wave 128x64; quadrants (mh,nh): P1 reads A(0),B(0); P2 B(1); P3 A(1); P4 none.
__global__ __launch_bounds__(512, 2) void gemm_qkv_kernel(const __hip_bfloat16* __restrict__ A,
                                                          const __hip_bfloat16* __restrict__ Bt,
                                                          __hip_bfloat16* __restrict__ Cbf,
                                                          __hip_bfloat16* __restrict__ vT,
                                                          int M, int N, int K) {
    constexpr int AREG = 32768;                // A region: 256 rows x 128 B
    constexpr int BUFB = 65536;                // A + B per K-tile
    constexpr int NT = 16;                     // K=1024 / BK=64
    __shared__ __align__(16) char smem[2 * BUFB];   // 128 KB

    const int tid = threadIdx.x;
    const int lane = tid & 63;
    const int wid = tid >> 6;

    // XCD-aware bijective swizzle (nwg = 192, % 8 == 0)
    int nwg = gridDim.x * gridDim.y;
    int lin = blockIdx.y * gridDim.x + blockIdx.x;
    int cpx = nwg >> 3;
    int swz = (lin & 7) * cpx + (lin >> 3);
    int bx = swz % gridDim.x;
    int by = swz / gridDim.x;

    const int rowBase = by * 256;
    const int colBase = bx * 256;

    const int wm = wid >> 2, wn = wid & 3;     // 2 x 4 waves, wave tile 128x64
    const int l15 = lane & 15, hi = lane >> 4;

    f32x4 acc[8][4];
#pragma unroll
    for (int m = 0; m < 8; ++m)
#pragma unroll
        for (int n = 0; n < 4; ++n) acc[m][n] = (f32x4){0.f, 0.f, 0.f, 0.f};

    // stage one 16 KB half (hs: 0=A rows 0-127, 1=A rows 128-255, 2=B 0-127, 3=B 128-255)
    auto STG = [&](int tt, int hs) {
        char* dst = smem + (tt & 1) * BUFB + hs * 16384 + (wid << 10);
#pragma unroll
        for (int j = 0; j < 2; ++j) {
            int o = j * 8192 + (wid << 10) + lane * 16;   // linear offset within half
            int row = o >> 7;                              // 0..127
            int ch = ((o >> 4) & 7) ^ (row & 7);           // inverse-swizzled k-chunk
            const __hip_bfloat16* src = (hs < 2)
                ? A + (size_t)(rowBase + hs * 128 + row) * K + tt * 64 + ch * 8
                : Bt + (size_t)(colBase + (hs - 2) * 128 + row) * K + tt * 64 + ch * 8;
            gload16(src, dst + j * 8192);
        }
    };
    auto LDA = [&](s16x8* fa, const char* buf, int mh) {
#pragma unroll
        for (int mf = 0; mf < 4; ++mf)
#pragma unroll
            for (int kk = 0; kk < 2; ++kk) {
                int r = wm * 128 + mh * 64 + mf * 16 + l15;
                int ch = kk * 4 + hi;
                fa[mf * 2 + kk] = *(const s16x8*)(buf + r * 128 + ((ch ^ (r & 7)) << 4));
            }
    };
    auto LDB = [&](s16x8* fb, const char* buf, int nh) {
#pragma unroll
        for (int nf = 0; nf < 2; ++nf)
#pragma unroll
            for (int kk = 0; kk < 2; ++kk) {
                int r = wn * 64 + nh * 32 + nf * 16 + l15;
                int ch = kk * 4 + hi;
                fb[nf * 2 + kk] = *(const s16x8*)(buf + AREG + r * 128 + ((ch ^ (r & 7)) << 4));
            }
    };
    auto MMA = [&](const s16x8* fa, const s16x8* fb, int mh, int nh) {
        __builtin_amdgcn_s_setprio(1);
#pragma unroll
        for (int kk = 0; kk < 2; ++kk)
#pragma unroll
            for (int mf = 0; mf < 4; ++mf)
#pragma unroll
                for (int nf = 0; nf < 2; ++nf)
                    acc[mh * 4 + mf][nh * 2 + nf] = __builtin_amdgcn_mfma_f32_16x16x32_bf16(
                        fa[mf * 2 + kk], fb[nf * 2 + kk], acc[mh * 4 + mf][nh * 2 + nf], 0, 0, 0);
        __builtin_amdgcn_s_setprio(0);
    };

    // prologue: stage tile 0 fully, certify, publish
    STG(0, 0); STG(0, 1); STG(0, 2); STG(0, 3);
    asm volatile("s_waitcnt vmcnt(0)" ::: "memory");
    __builtin_amdgcn_s_barrier();
    cfence();

    s16x8 fa[8], fb0[4], fb1[4];
    for (int t = 0; t < NT; ++t) {
        const char* buf = smem + (t & 1) * BUFB;
        const bool pf = (t + 1 < NT);
        // P1: quadrant (0,0)
        LDA(fa, buf, 0); LDB(fb0, buf, 0);
        if (pf) STG(t + 1, 0);
        phasebar();
        MMA(fa, fb0, 0, 0);
        phasebar();
        // P2: quadrant (0,1)
        LDB(fb1, buf, 1);
        if (pf) STG(t + 1, 1);
        phasebar();
        MMA(fa, fb1, 0, 1);
        phasebar();
        // P3: quadrant (1,0)
        LDA(fa, buf, 1);
        if (pf) STG(t + 1, 2);
        phasebar();
        MMA(fa, fb0, 1, 0);
        phasebar();
        // P4: quadrant (1,1)
        if (pf) STG(t + 1, 3);
        phasebar();
        MMA(fa, fb1, 1, 1);
        asm volatile("s_waitcnt vmcnt(0)" ::: "memory");   // tile t+1 certified (own loads)
        phasebar();                                         // published to all waves
    }

    if (colBase < 2 * D_) {                     // q,k section: direct stores
#pragma unroll
        for (int mf = 0; mf < 8; ++mf)
#pragma unroll
            for (int nf = 0; nf < 4; ++nf) {
                int col = colBase + wn * 64 + nf * 16 + l15;
                int row0 = rowBase + wm * 128 + mf * 16 + 4 * hi;
#pragma unroll
                for (int r = 0; r < 4; ++r)
                    Cbf[(size_t)(row0 + r) * N + col] = __float2bfloat16(acc[mf][nf][r]);
            }
    } else {                                    // v section: 2-pass LDS transpose -> vT
        __syncthreads();                        // all waves done with LDS main loop
        int bb2 = rowBase >> 11, i0 = rowBase & (L_ - 1);
#pragma unroll
        for (int p = 0; p < 2; ++p) {
            if (p) __syncthreads();             // pass-0 reads done before overwrite
            if ((wn >> 1) == p) {
#pragma unroll
                for (int mf = 0; mf < 8; ++mf)
#pragma unroll
                    for (int nf = 0; nf < 4; ++nf) {
                        int clp = (wn & 1) * 64 + nf * 16 + l15;
                        int rlb = wm * 128 + mf * 16 + 4 * hi;
                        s16x4 pk;
#pragma unroll
                        for (int r = 0; r < 4; ++r) {
                            __hip_bfloat16 t = __float2bfloat16(acc[mf][nf][r]);
                            pk[r] = *reinterpret_cast<short*>(&t);
                        }
                        *(s16x4*)(smem + clp * 528 + rlb * 2) = pk;
                    }
            }
            __syncthreads();
            {
                int c = tid >> 2, qd = tid & 3;
                int gcol = colBase + p * 128 + c - 2 * D_;
                int hh = gcol >> 6, dd = gcol & 63;
                __hip_bfloat16* dstp = vT + ((size_t)(bb2 * H_ + hh) * DH + dd) * L_ + i0 + qd * 64;
#pragma unroll
                for (int ch = 0; ch < 8; ++ch)
                    *(s16x8*)(dstp + ch * 8) = *(const s16x8*)(smem + c * 528 + qd * 128 + ch * 16);
            }
        }
    }
}

// ---------------- out-proj GEMM (round-9 proven): 128 x 64 tile, BK=32, 4 buffers ----------------
__global__ __launch_bounds__(256, 3) void gemm_proj_kernel(const __hip_bfloat16* __restrict__ A,
                                                           const __hip_bfloat16* __restrict__ Bt,
                                                           float* __restrict__ Cf,
                                                           const float* __restrict__ resid,
                                                           int M, int N, int K) {
    constexpr int BM = 128, BN = 64;
    constexpr int ATILE = BM * 64;             // 8192
    constexpr int BTILE = BN * 64;             // 4096
    constexpr int BUFB = ATILE + BTILE;        // 12288
    __shared__ __align__(16) char smem[4 * BUFB];   // 48 KB

    const int tid = threadIdx.x;
    const int lane = tid & 63;
    const int wid = tid >> 6;

    int nwg = gridDim.x * gridDim.y;
    int lin = blockIdx.y * gridDim.x + blockIdx.x;
    int cpx = nwg >> 3;
    int swz = (lin & 7) * cpx + (lin >> 3);
    int bx = swz % gridDim.x;
    int by = swz / gridDim.x;

    const int rowBase = by * BM;
    const int colBase = bx * BN;
    const int NT = K >> 5;

    const int r0 = tid >> 2;                   // 0..63
    const int cS = ((tid & 3) ^ ((r0 ^ (r0 >> 2)) & 3)) << 3;
    const __hip_bfloat16* aG = A + (size_t)(rowBase + r0) * K + cS;
    const __hip_bfloat16* bG = Bt + (size_t)(colBase + r0) * K + cS;
    const int dstW = wid << 10;

    const int wm = wid >> 1, wn = wid & 1;
    const int l15 = lane & 15, hi = lane >> 4;
    const int swzl = (l15 ^ (l15 >> 2)) & 3;
    const int aRd = wm * 4096 + l15 * 64 + ((hi ^ swzl) << 4);
    const int bRd = ATILE + wn * 2048 + l15 * 64 + ((hi ^ swzl) << 4);

    f32x4 acc[4][2];
#pragma unroll
    for (int m = 0; m < 4; ++m)
#pragma unroll
        for (int n = 0; n < 2; ++n) acc[m][n] = (f32x4){0.f, 0.f, 0.f, 0.f};

    auto STAGE = [&](int tt) {
        char* base = smem + (tt & 3) * BUFB + dstW;
        const __hip_bfloat16* as = aG + (size_t)tt * 32;
        const __hip_bfloat16* bs = bG + (size_t)tt * 32;
        gload16(as, base);
        gload16(as + (size_t)64 * K, base + 4096);
        gload16(bs, base + ATILE);
    };

    STAGE(0);
    STAGE(1);

    for (int t = 0; t < NT; ++t) {
        if (t + 2 < NT) {
            STAGE(t + 2);
            asm volatile("s_waitcnt vmcnt(6)" ::: "memory");
        } else if (t + 1 < NT) {
            asm volatile("s_waitcnt vmcnt(3)" ::: "memory");
        } else {
            asm volatile("s_waitcnt vmcnt(0)" ::: "memory");
        }
        asm volatile("s_waitcnt lgkmcnt(0)" ::: "memory");
        __builtin_amdgcn_s_barrier();
        cfence();

        const char* tb = smem + (t & 3) * BUFB;
        s16x8 af[4], bf[2];
#pragma unroll
        for (int mf = 0; mf < 4; ++mf)
            af[mf] = *(const s16x8*)(tb + aRd + mf * 1024);
#pragma unroll
        for (int nf = 0; nf < 2; ++nf)
            bf[nf] = *(const s16x8*)(tb + bRd + nf * 1024);

        __builtin_amdgcn_s_setprio(1);
#pragma unroll
        for (int mf = 0; mf < 4; ++mf)
#pragma unroll
            for (int nf = 0; nf < 2; ++nf)
                acc[mf][nf] = __builtin_amdgcn_mfma_f32_16x16x32_bf16(af[mf], bf[nf],
                                                                      acc[mf][nf], 0, 0, 0);
        __builtin_amdgcn_s_setprio(0);
    }

#pragma unroll
    for (int mf = 0; mf < 4; ++mf)
#pragma unroll
        for (int nf = 0; nf < 2; ++nf) {
            int col = colBase + wn * 32 + nf * 16 + l15;
            int row0 = rowBase + wm * 64 + mf * 16 + 4 * hi;
#pragma unroll
            for (int r = 0; r < 4; ++r)
                Cf[(size_t)(row0 + r) * N + col] = acc[mf][nf][r] + resid[(size_t)(row0 + r) * N + col];
        }
}

// ---------------- barrier-free LDS-free MFMA banded attention (round-8, proven) ----------------
__global__ __launch_bounds__(128, 2) void attn_mfma_kernel(const __hip_bfloat16* __restrict__ qkv,
                                                           const __hip_bfloat16* __restrict__ vT,
                                                           __hip_bfloat16* __restrict__ attn) {
    int tid = threadIdx.x;
    int w = tid >> 6;
    int lane = tid & 63;
    int l31 = lane & 31, hi1 = lane >> 5;
    int tq = blockIdx.x, h = blockIdx.y, b = blockIdx.z;
    int qbase = tq * 64 + 32 * w;
    int kb = qbase - HALF;
    int qg = qbase + l31;
    const __hip_bfloat16* qkvb = qkv + (size_t)(b * L_) * QKV_N;
    const __hip_bfloat16* vTg = vT + (size_t)(b * H_ + h) * DH * L_;

    s16x8 qf[4];
#pragma unroll
    for (int kk = 0; kk < 4; ++kk)
        qf[kk] = *(const s16x8*)(qkvb + (size_t)qg * QKV_N + h * DH + kk * 16 + hi1 * 8);

    f32x16 T[5];
#pragma unroll
    for (int kt = 0; kt < 5; ++kt) T[kt] = (f32x16)(0.f);
#pragma unroll
    for (int kt = 0; kt < 5; ++kt) {
        int keyg = kb + 32 * kt + l31;
        int kc = keyg < 0 ? 0 : (keyg > L_ - 1 ? L_ - 1 : keyg);
        const __hip_bfloat16* kp = qkvb + (size_t)kc * QKV_N + D_ + h * DH + hi1 * 8;
#pragma unroll
        for (int kk = 0; kk < 4; ++kk) {
            s16x8 kf = *(const s16x8*)(kp + kk * 16);
            T[kt] = __builtin_amdgcn_mfma_f32_32x32x16_bf16(kf, qf[kk], T[kt], 0, 0, 0);
        }
    }

    float mx = -1e30f;
#pragma unroll
    for (int kt = 0; kt < 5; ++kt) {
#pragma unroll
        for (int r = 0; r < 16; ++r) {
            int koff = (r & 3) + 8 * (r >> 2) + 4 * hi1;
            int keyg = kb + 32 * kt + koff;
            int del = keyg - qg;
            bool ok = (del >= -HALF) && (del <= HALF) && (keyg >= 0) && (keyg < L_);
            float t = ok ? T[kt][r] * 0.125f : -1e30f;
            T[kt][r] = t;
            mx = fmaxf(mx, t);
        }
    }
    mx = fmaxf(mx, __shfl_xor(mx, 32));
    float sum = 0.f;
#pragma unroll
    for (int kt = 0; kt < 5; ++kt) {
#pragma unroll
        for (int r = 0; r < 16; ++r) {
            float p = __expf(T[kt][r] - mx);
            T[kt][r] = p;
            sum += p;
        }
    }
    sum += __shfl_xor(sum, 32);
    float inv = 1.0f / sum;

    u32x4 pu[10];
#pragma unroll
    for (int kt = 0; kt < 5; ++kt) {
#pragma unroll
        for (int s = 0; s < 2; ++s) {
            unsigned P0, P1, P2, P3;
            asm("v_cvt_pk_bf16_f32 %0, %1, %2" : "=v"(P0) : "v"(T[kt][8 * s + 0]), "v"(T[kt][8 * s + 1]));
            asm("v_cvt_pk_bf16_f32 %0, %1, %2" : "=v"(P1) : "v"(T[kt][8 * s + 2]), "v"(T[kt][8 * s + 3]));
            asm("v_cvt_pk_bf16_f32 %0, %1, %2" : "=v"(P2) : "v"(T[kt][8 * s + 4]), "v"(T[kt][8 * s + 5]));
            asm("v_cvt_pk_bf16_f32 %0, %1, %2" : "=v"(P3) : "v"(T[kt][8 * s + 6]), "v"(T[kt][8 * s + 7]));
            u32x2 sA = __builtin_amdgcn_permlane32_swap(P0, P2, false, false);
            u32x2 sB = __builtin_amdgcn_permlane32_swap(P1, P3, false, false);
            pu[2 * kt + s] = (u32x4){sA[0], sB[0], sA[1], sB[1]};
        }
    }

    f32x16 O[2];
#pragma unroll
    for (int dt = 0; dt < 2; ++dt) O[dt] = (f32x16)(0.f);
#pragma unroll
    for (int t = 0; t < 10; ++t) {
        int kv = kb + 16 * t + 8 * hi1;
        kv = kv < 0 ? 0 : (kv > L_ - 8 ? L_ - 8 : kv);
        s16x8 pf = __builtin_bit_cast(s16x8, pu[t]);
#pragma unroll
        for (int dt = 0; dt < 2; ++dt) {
            s16x8 vf = *(const s16x8*)(vTg + (size_t)(32 * dt + l31) * L_ + kv);
            O[dt] = __builtin_amdgcn_mfma_f32_32x32x16_bf16(vf, pf, O[dt], 0, 0, 0);
        }
    }

    __hip_bfloat16* ob = attn + (size_t)(b * L_ + qg) * D_ + h * DH;
#pragma unroll
    for (int dt = 0; dt < 2; ++dt) {
#pragma unroll
        for (int rr = 0; rr < 4; ++rr) {
            s16x4 pk4;
#pragma unroll
            for (int j = 0; j < 4; ++j) {
                __hip_bfloat16 tb = __float2bfloat16(O[dt][4 * rr + j] * inv);
                pk4[j] = *reinterpret_cast<short*>(&tb);
            }
            *(s16x4*)(ob + 32 * dt + 8 * rr + 4 * hi1) = pk4;
        }
    }
}

extern "C" void kernel_launch(void* const* d_in, const int* in_sizes, int n_in,
                              void* d_out, int out_size, void* d_ws, size_t ws_size,
                              hipStream_t stream) {
    const float* x      = (const float*)d_in[0];
    const float* w_norm = (const float*)d_in[1];
    const float* w_qkv  = (const float*)d_in[2];
    const float* w_out  = (const float*)d_in[3];

    char* ws = (char*)d_ws;
    __hip_bfloat16* xn   = (__hip_bfloat16*)(ws);                        //  8 MiB
    __hip_bfloat16* wq   = (__hip_bfloat16*)(ws + (8u  << 20));          //  6 MiB
    __hip_bfloat16* wo   = (__hip_bfloat16*)(ws + (14u << 20));          //  2 MiB
    __hip_bfloat16* qkv  = (__hip_bfloat16*)(ws + (16u << 20));          // 24 MiB (q,k used)
    __hip_bfloat16* attn = (__hip_bfloat16*)(ws + (40u << 20));          //  8 MiB
    __hip_bfloat16* vT   = (__hip_bfloat16*)(ws + (48u << 20));          //  8 MiB
    float* out = (float*)d_out;

    // fused weight conversion + RMSNorm
    prep_kernel<<<4096 + M_ROWS / 4, 256, 0, stream>>>(x, w_norm, w_qkv, w_out, xn, wq, wo);

    // QKV GEMM: [4096,1024] x [3072,1024]^T -> q,k bf16 + vT transposed (256^2, 4-phase)
    gemm_qkv_kernel<<<dim3(QKV_N / 256, M_ROWS / 256), 512, 0, stream>>>(
        xn, wq, qkv, vT, M_ROWS, QKV_N, D_);

    // MFMA banded attention -> bf16 [4096,1024]
    attn_mfma_kernel<<<dim3(L_ / 64, H_, B_), 128, 0, stream>>>(qkv, vT, attn);

    // out proj + residual: [4096,1024] x [1024,1024]^T + x -> f32 d_out
    gemm_proj_kernel<<<dim3(D_ / 64, M_ROWS / 128), 256, 0, stream>>>(
        attn, wo, out, x, M_ROWS, D_, D_);
}

// Round 13
// 86.675 us; speedup vs baseline: 1.0534x; 1.0347x over previous
//
#include <hip/hip_runtime.h>
#include <hip/hip_bf16.h>
#include <cstdint>

typedef float f32x4 __attribute__((ext_vector_type(4)));
typedef float f32x16 __attribute__((ext_vector_type(16)));
typedef short s16x8 __attribute__((ext_vector_type(8)));
typedef short s16x4 __attribute__((ext_vector_type(4)));
typedef unsigned int u32x2 __attribute__((ext_vector_type(2)));
typedef unsigned int u32x4 __attribute__((ext_vector_type(4)));

constexpr int B_ = 2, L_ = 2048, D_ = 1024, H_ = 16, DH = 64, HALF = 64;
constexpr int M_ROWS = B_ * L_;   // 4096
constexpr int QKV_N = 3 * D_;     // 3072

__device__ __forceinline__ void gload16(const void* g, void* l) {
    __builtin_amdgcn_global_load_lds(
        (const __attribute__((address_space(1))) unsigned int*)g,
        (__attribute__((address_space(3))) unsigned int*)l, 16, 0, 0);
}

__device__ __forceinline__ void cfence() {
    __builtin_amdgcn_sched_barrier(0);
    asm volatile("" ::: "memory");
}

// ---------------- fused prep: weight cvt (blocks 0..4095) + RMSNorm (4096..5119) ----------------
__global__ __launch_bounds__(256) void prep_kernel(const float* __restrict__ x,
                                                   const float* __restrict__ wn,
                                                   const float* __restrict__ wq,
                                                   const float* __restrict__ wo,
                                                   __hip_bfloat16* __restrict__ xn,
                                                   __hip_bfloat16* __restrict__ oq,
                                                   __hip_bfloat16* __restrict__ oo) {
    constexpr int NQ4 = QKV_N * D_ / 4;              // 786432
    constexpr int NCVT = NQ4 + D_ * D_ / 4;          // 1048576
    constexpr int CVTBLK = NCVT / 256;               // 4096
    int bid = blockIdx.x;
    if (bid < CVTBLK) {
        int i = bid * 256 + threadIdx.x;
        const float* src; __hip_bfloat16* dst; int j;
        if (i < NQ4) { src = wq; dst = oq; j = i; }
        else         { src = wo; dst = oo; j = i - NQ4; }
        float4 v = reinterpret_cast<const float4*>(src)[j];
        s16x4 pk;
        float vals[4] = {v.x, v.y, v.z, v.w};
#pragma unroll
        for (int e = 0; e < 4; ++e) {
            __hip_bfloat16 t = __float2bfloat16(vals[e]);
            pk[e] = *reinterpret_cast<short*>(&t);
        }
        *(s16x4*)(dst + (size_t)j * 4) = pk;
    } else {
        int w = threadIdx.x >> 6, lane = threadIdx.x & 63;
        int row = (bid - CVTBLK) * 4 + w;
        const float4* xr = reinterpret_cast<const float4*>(x + (size_t)row * D_);
        const float4* wr = reinterpret_cast<const float4*>(wn);
        float4 v[4];
        float ss = 0.f;
#pragma unroll
        for (int c = 0; c < 4; ++c) {
            v[c] = xr[c * 64 + lane];
            ss += v[c].x * v[c].x + v[c].y * v[c].y + v[c].z * v[c].z + v[c].w * v[c].w;
        }
#pragma unroll
        for (int off = 32; off; off >>= 1) ss += __shfl_xor(ss, off);
        float rinv = rsqrtf(ss * (1.0f / D_) + 1e-6f);
#pragma unroll
        for (int c = 0; c < 4; ++c) {
            float4 wv = wr[c * 64 + lane];
            s16x4 pk;
            float vals[4] = {v[c].x * rinv * wv.x, v[c].y * rinv * wv.y,
                             v[c].z * rinv * wv.z, v[c].w * rinv * wv.w};
#pragma unroll
            for (int e = 0; e < 4; ++e) {
                __hip_bfloat16 t = __float2bfloat16(vals[e]);
                pk[e] = *reinterpret_cast<short*>(&t);
            }
            *(s16x4*)(xn + (size_t)row * D_ + (c * 64 + lane) * 4) = pk;
        }
    }
}

// ---------------- QKV GEMM: 256x256, BK=32, 4 buffers, depth-2, 4-phase (T3+T4) ----------------
// 512 thr / 8 waves (2Mx4N), per-wave 128x64. LDS 4 x 32KB (A 16K + B 16K pair-packed rows).
// Tile t phases: P1 {STG(t+2,A0); vmcnt(5)+bar [certifies ALL tile-t units, staged >=4
// phases ago]; ds_read A0,B0,B1; 8 MFMA} P2 {STG A1; bar; ds_read A1; 8 MFMA}
// P3 {STG B0; bar; 8 MFMA} P4 {STG B1; bar; 8 MFMA}.  vmcnt never 0 mid-loop.
// LDS row-pair packing (r9-verified): LDS-row R slot s holds M[2R+(u>>2)][(u&3)*8], u=s^(R&7).
__global__ __launch_bounds__(512, 2) void gemm_qkv_kernel(const __hip_bfloat16* __restrict__ A,
                                                          const __hip_bfloat16* __restrict__ Bt,
                                                          __hip_bfloat16* __restrict__ Cbf,
                                                          __hip_bfloat16* __restrict__ vT,
                                                          int M, int N, int K) {
    constexpr int BOFF = 16384;                // B region within buffer
    constexpr int BUFB = 32768;
    constexpr int NT = 32;                     // K=1024 / BK=32
    __shared__ __align__(16) char smem[4 * BUFB];   // 128 KB

    const int tid = threadIdx.x;
    const int lane = tid & 63;
    const int wid = tid >> 6;

    // XCD-aware bijective swizzle (nwg = 192, % 8 == 0)
    int nwg = gridDim.x * gridDim.y;
    int lin = blockIdx.y * gridDim.x + blockIdx.x;
    int cpx = nwg >> 3;
    int swz = (lin & 7) * cpx + (lin >> 3);
    int bx = swz % gridDim.x;
    int by = swz / gridDim.x;

    const int rowBase = by * 256;
    const int colBase = bx * 256;

    // ---- staging maps: thread -> (LDS row R = tid>>3 within unit, slot s = tid&7) ----
    const int sR = tid >> 3;                   // 0..63
    const int su = (tid & 7) ^ (sR & 7);
    const int sMrow = 2 * sR + (su >> 2);      // 0..127 within half
    const int sCol = (su & 3) * 8;
    const __hip_bfloat16* aG0 = A + (size_t)(rowBase + sMrow) * K + sCol;
    const __hip_bfloat16* aG1 = A + (size_t)(rowBase + 128 + sMrow) * K + sCol;
    const __hip_bfloat16* bG0 = Bt + (size_t)(colBase + sMrow) * K + sCol;
    const __hip_bfloat16* bG1 = Bt + (size_t)(colBase + 128 + sMrow) * K + sCol;
    const int dstW = wid << 10;                // + lane*16 by HW

    // ---- fragment read coords ----
    const int wm = wid >> 2, wn = wid & 3;     // 2 x 4 waves, wave tile 128x64
    const int l15 = lane & 15, hi = lane >> 4;
    const int sRd = (((l15 & 1) << 2) | hi) ^ ((l15 >> 1) & 7);
    const int aRdB = (wm * 64 + (l15 >> 1)) * 128 + sRd * 16;          // + mh*4096 + mf*1024
    const int bRdB = BOFF + (wn * 32 + (l15 >> 1)) * 128 + sRd * 16;   // + nh*2048 + nf*1024

    f32x4 acc[8][4];
#pragma unroll
    for (int m = 0; m < 8; ++m)
#pragma unroll
        for (int n = 0; n < 4; ++n) acc[m][n] = (f32x4){0.f, 0.f, 0.f, 0.f};

    auto STG = [&](int tt, int u) {            // u: 0=A0 1=A1 2=B0 3=B1 (literal at call site)
        char* dst = smem + (tt & 3) * BUFB + ((u & 2) ? BOFF : 0) + ((u & 1) << 13) + dstW;
        const __hip_bfloat16* src = (u == 0) ? aG0 : (u == 1) ? aG1 : (u == 2) ? bG0 : bG1;
        gload16(src + (size_t)tt * 32, dst);
    };
    auto LDA = [&](s16x8* fa, const char* buf, int mh) {
#pragma unroll
        for (int mf = 0; mf < 4; ++mf)
            fa[mf] = *(const s16x8*)(buf + aRdB + mh * 4096 + mf * 1024);
    };
    auto LDB = [&](s16x8* fb, const char* buf, int nh) {
#pragma unroll
        for (int nf = 0; nf < 2; ++nf)
            fb[nf] = *(const s16x8*)(buf + bRdB + nh * 2048 + nf * 1024);
    };
    auto MMA = [&](const s16x8* fa, const s16x8* fb, int mh, int nh) {
        __builtin_amdgcn_s_setprio(1);
#pragma unroll
        for (int mf = 0; mf < 4; ++mf)
#pragma unroll
            for (int nf = 0; nf < 2; ++nf)
                acc[mh * 4 + mf][nh * 2 + nf] = __builtin_amdgcn_mfma_f32_16x16x32_bf16(
                    fa[mf], fb[nf], acc[mh * 4 + mf][nh * 2 + nf], 0, 0, 0);
        __builtin_amdgcn_s_setprio(0);
    };

    // prologue: stage tiles 0 and 1 fully (8 loads/thread in flight)
    STG(0, 0); STG(0, 1); STG(0, 2); STG(0, 3);
    STG(1, 0); STG(1, 1); STG(1, 2); STG(1, 3);

    s16x8 fa0[4], fa1[4], fb0[2], fb1[2];
    for (int t = 0; t < NT; ++t) {
        const char* buf = smem + (t & 3) * BUFB;
        const bool pf = (t + 2 < NT);
        // ---- P1 ----
        if (pf) STG(t + 2, 0);
        if (pf)                asm volatile("s_waitcnt vmcnt(5)\n\ts_barrier" ::: "memory");
        else if (t + 1 < NT)   asm volatile("s_waitcnt vmcnt(4)\n\ts_barrier" ::: "memory");
        else                   asm volatile("s_waitcnt vmcnt(0)\n\ts_barrier" ::: "memory");
        cfence();
        LDA(fa0, buf, 0); LDB(fb0, buf, 0); LDB(fb1, buf, 1);
        MMA(fa0, fb0, 0, 0);
        // ---- P2 ----
        if (pf) STG(t + 2, 1);
        cfence(); __builtin_amdgcn_s_barrier(); cfence();
        LDA(fa1, buf, 1);
        MMA(fa0, fb1, 0, 1);
        // ---- P3 ----
        if (pf) STG(t + 2, 2);
        cfence(); __builtin_amdgcn_s_barrier(); cfence();
        MMA(fa1, fb0, 1, 0);
        // ---- P4 ----
        if (pf) STG(t + 2, 3);
        cfence(); __builtin_amdgcn_s_barrier(); cfence();
        MMA(fa1, fb1, 1, 1);
    }

    if (colBase < 2 * D_) {                     // q,k section: direct stores
#pragma unroll
        for (int mf = 0; mf < 8; ++mf)
#pragma unroll
            for (int nf = 0; nf < 4; ++nf) {
                int col = colBase + wn * 64 + nf * 16 + l15;
                int row0 = rowBase + wm * 128 + mf * 16 + 4 * hi;
#pragma unroll
                for (int r = 0; r < 4; ++r)
                    Cbf[(size_t)(row0 + r) * N + col] = __float2bfloat16(acc[mf][nf][r]);
            }
    } else {                                    // v section: 2-pass LDS transpose -> vT
        __syncthreads();                        // all waves done with LDS main loop
        int bb2 = rowBase >> 11, i0 = rowBase & (L_ - 1);
#pragma unroll
        for (int p = 0; p < 2; ++p) {
            if (p) __syncthreads();             // pass-0 reads done before overwrite
            if ((wn >> 1) == p) {
#pragma unroll
                for (int mf = 0; mf < 8; ++mf)
#pragma unroll
                    for (int nf = 0; nf < 4; ++nf) {
                        int clp = (wn & 1) * 64 + nf * 16 + l15;
                        int rlb = wm * 128 + mf * 16 + 4 * hi;
                        s16x4 pk;
#pragma unroll
                        for (int r = 0; r < 4; ++r) {
                            __hip_bfloat16 t = __float2bfloat16(acc[mf][nf][r]);
                            pk[r] = *reinterpret_cast<short*>(&t);
                        }
                        *(s16x4*)(smem + clp * 528 + rlb * 2) = pk;
                    }
            }
            __syncthreads();
            {
                int c = tid >> 2, qd = tid & 3;
                int gcol = colBase + p * 128 + c - 2 * D_;
                int hh = gcol >> 6, dd = gcol & 63;
                __hip_bfloat16* dstp = vT + ((size_t)(bb2 * H_ + hh) * DH + dd) * L_ + i0 + qd * 64;
#pragma unroll
                for (int ch = 0; ch < 8; ++ch)
                    *(s16x8*)(dstp + ch * 8) = *(const s16x8*)(smem + c * 528 + qd * 128 + ch * 16);
            }
        }
    }
}

// ---------------- out-proj GEMM (round-9 proven): 128 x 64 tile, BK=32, 4 buffers ----------------
__global__ __launch_bounds__(256, 3) void gemm_proj_kernel(const __hip_bfloat16* __restrict__ A,
                                                           const __hip_bfloat16* __restrict__ Bt,
                                                           float* __restrict__ Cf,
                                                           const float* __restrict__ resid,
                                                           int M, int N, int K) {
    constexpr int BM = 128, BN = 64;
    constexpr int ATILE = BM * 64;             // 8192
    constexpr int BTILE = BN * 64;             // 4096
    constexpr int BUFB = ATILE + BTILE;        // 12288
    __shared__ __align__(16) char smem[4 * BUFB];   // 48 KB

    const int tid = threadIdx.x;
    const int lane = tid & 63;
    const int wid = tid >> 6;

    int nwg = gridDim.x * gridDim.y;
    int lin = blockIdx.y * gridDim.x + blockIdx.x;
    int cpx = nwg >> 3;
    int swz = (lin & 7) * cpx + (lin >> 3);
    int bx = swz % gridDim.x;
    int by = swz / gridDim.x;

    const int rowBase = by * BM;
    const int colBase = bx * BN;
    const int NT = K >> 5;

    const int r0 = tid >> 2;                   // 0..63
    const int cS = ((tid & 3) ^ ((r0 ^ (r0 >> 2)) & 3)) << 3;
    const __hip_bfloat16* aG = A + (size_t)(rowBase + r0) * K + cS;
    const __hip_bfloat16* bG = Bt + (size_t)(colBase + r0) * K + cS;
    const int dstW = wid << 10;

    const int wm = wid >> 1, wn = wid & 1;
    const int l15 = lane & 15, hi = lane >> 4;
    const int swzl = (l15 ^ (l15 >> 2)) & 3;
    const int aRd = wm * 4096 + l15 * 64 + ((hi ^ swzl) << 4);
    const int bRd = ATILE + wn * 2048 + l15 * 64 + ((hi ^ swzl) << 4);

    f32x4 acc[4][2];
#pragma unroll
    for (int m = 0; m < 4; ++m)
#pragma unroll
        for (int n = 0; n < 2; ++n) acc[m][n] = (f32x4){0.f, 0.f, 0.f, 0.f};

    auto STAGE = [&](int tt) {
        char* base = smem + (tt & 3) * BUFB + dstW;
        const __hip_bfloat16* as = aG + (size_t)tt * 32;
        const __hip_bfloat16* bs = bG + (size_t)tt * 32;
        gload16(as, base);
        gload16(as + (size_t)64 * K, base + 4096);
        gload16(bs, base + ATILE);
    };

    STAGE(0);
    STAGE(1);

    for (int t = 0; t < NT; ++t) {
        if (t + 2 < NT) {
            STAGE(t + 2);
            asm volatile("s_waitcnt vmcnt(6)" ::: "memory");
        } else if (t + 1 < NT) {
            asm volatile("s_waitcnt vmcnt(3)" ::: "memory");
        } else {
            asm volatile("s_waitcnt vmcnt(0)" ::: "memory");
        }
        asm volatile("s_waitcnt lgkmcnt(0)" ::: "memory");
        __builtin_amdgcn_s_barrier();
        cfence();

        const char* tb = smem + (t & 3) * BUFB;
        s16x8 af[4], bf[2];
#pragma unroll
        for (int mf = 0; mf < 4; ++mf)
            af[mf] = *(const s16x8*)(tb + aRd + mf * 1024);
#pragma unroll
        for (int nf = 0; nf < 2; ++nf)
            bf[nf] = *(const s16x8*)(tb + bRd + nf * 1024);

        __builtin_amdgcn_s_setprio(1);
#pragma unroll
        for (int mf = 0; mf < 4; ++mf)
#pragma unroll
            for (int nf = 0; nf < 2; ++nf)
                acc[mf][nf] = __builtin_amdgcn_mfma_f32_16x16x32_bf16(af[mf], bf[nf],
                                                                      acc[mf][nf], 0, 0, 0);
        __builtin_amdgcn_s_setprio(0);
    }

#pragma unroll
    for (int mf = 0; mf < 4; ++mf)
#pragma unroll
        for (int nf = 0; nf < 2; ++nf) {
            int col = colBase + wn * 32 + nf * 16 + l15;
            int row0 = rowBase + wm * 64 + mf * 16 + 4 * hi;
#pragma unroll
            for (int r = 0; r < 4; ++r)
                Cf[(size_t)(row0 + r) * N + col] = acc[mf][nf][r] + resid[(size_t)(row0 + r) * N + col];
        }
}

// ---------------- barrier-free LDS-free MFMA banded attention (round-8, proven) ----------------
__global__ __launch_bounds__(128, 2) void attn_mfma_kernel(const __hip_bfloat16* __restrict__ qkv,
                                                           const __hip_bfloat16* __restrict__ vT,
                                                           __hip_bfloat16* __restrict__ attn) {
    int tid = threadIdx.x;
    int w = tid >> 6;
    int lane = tid & 63;
    int l31 = lane & 31, hi1 = lane >> 5;
    int tq = blockIdx.x, h = blockIdx.y, b = blockIdx.z;
    int qbase = tq * 64 + 32 * w;
    int kb = qbase - HALF;
    int qg = qbase + l31;
    const __hip_bfloat16* qkvb = qkv + (size_t)(b * L_) * QKV_N;
    const __hip_bfloat16* vTg = vT + (size_t)(b * H_ + h) * DH * L_;

    s16x8 qf[4];
#pragma unroll
    for (int kk = 0; kk < 4; ++kk)
        qf[kk] = *(const s16x8*)(qkvb + (size_t)qg * QKV_N + h * DH + kk * 16 + hi1 * 8);

    f32x16 T[5];
#pragma unroll
    for (int kt = 0; kt < 5; ++kt) T[kt] = (f32x16)(0.f);
#pragma unroll
    for (int kt = 0; kt < 5; ++kt) {
        int keyg = kb + 32 * kt + l31;
        int kc = keyg < 0 ? 0 : (keyg > L_ - 1 ? L_ - 1 : keyg);
        const __hip_bfloat16* kp = qkvb + (size_t)kc * QKV_N + D_ + h * DH + hi1 * 8;
#pragma unroll
        for (int kk = 0; kk < 4; ++kk) {
            s16x8 kf = *(const s16x8*)(kp + kk * 16);
            T[kt] = __builtin_amdgcn_mfma_f32_32x32x16_bf16(kf, qf[kk], T[kt], 0, 0, 0);
        }
    }

    float mx = -1e30f;
#pragma unroll
    for (int kt = 0; kt < 5; ++kt) {
#pragma unroll
        for (int r = 0; r < 16; ++r) {
            int koff = (r & 3) + 8 * (r >> 2) + 4 * hi1;
            int keyg = kb + 32 * kt + koff;
            int del = keyg - qg;
            bool ok = (del >= -HALF) && (del <= HALF) && (keyg >= 0) && (keyg < L_);
            float t = ok ? T[kt][r] * 0.125f : -1e30f;
            T[kt][r] = t;
            mx = fmaxf(mx, t);
        }
    }
    mx = fmaxf(mx, __shfl_xor(mx, 32));
    float sum = 0.f;
#pragma unroll
    for (int kt = 0; kt < 5; ++kt) {
#pragma unroll
        for (int r = 0; r < 16; ++r) {
            float p = __expf(T[kt][r] - mx);
            T[kt][r] = p;
            sum += p;
        }
    }
    sum += __shfl_xor(sum, 32);
    float inv = 1.0f / sum;

    u32x4 pu[10];
#pragma unroll
    for (int kt = 0; kt < 5; ++kt) {
#pragma unroll
        for (int s = 0; s < 2; ++s) {
            unsigned P0, P1, P2, P3;
            asm("v_cvt_pk_bf16_f32 %0, %1, %2" : "=v"(P0) : "v"(T[kt][8 * s + 0]), "v"(T[kt][8 * s + 1]));
            asm("v_cvt_pk_bf16_f32 %0, %1, %2" : "=v"(P1) : "v"(T[kt][8 * s + 2]), "v"(T[kt][8 * s + 3]));
            asm("v_cvt_pk_bf16_f32 %0, %1, %2" : "=v"(P2) : "v"(T[kt][8 * s + 4]), "v"(T[kt][8 * s + 5]));
            asm("v_cvt_pk_bf16_f32 %0, %1, %2" : "=v"(P3) : "v"(T[kt][8 * s + 6]), "v"(T[kt][8 * s + 7]));
            u32x2 sA = __builtin_amdgcn_permlane32_swap(P0, P2, false, false);
            u32x2 sB = __builtin_amdgcn_permlane32_swap(P1, P3, false, false);
            pu[2 * kt + s] = (u32x4){sA[0], sB[0], sA[1], sB[1]};
        }
    }

    f32x16 O[2];
#pragma unroll
    for (int dt = 0; dt < 2; ++dt) O[dt] = (f32x16)(0.f);
#pragma unroll
    for (int t = 0; t < 10; ++t) {
        int kv = kb + 16 * t + 8 * hi1;
        kv = kv < 0 ? 0 : (kv > L_ - 8 ? L_ - 8 : kv);
        s16x8 pf = __builtin_bit_cast(s16x8, pu[t]);
#pragma unroll
        for (int dt = 0; dt < 2; ++dt) {
            s16x8 vf = *(const s16x8*)(vTg + (size_t)(32 * dt + l31) * L_ + kv);
            O[dt] = __builtin_amdgcn_mfma_f32_32x32x16_bf16(vf, pf, O[dt], 0, 0, 0);
        }
    }

    __hip_bfloat16* ob = attn + (size_t)(b * L_ + qg) * D_ + h * DH;
#pragma unroll
    for (int dt = 0; dt < 2; ++dt) {
#pragma unroll
        for (int rr = 0; rr < 4; ++rr) {
            s16x4 pk4;
#pragma unroll
            for (int j = 0; j < 4; ++j) {
                __hip_bfloat16 tb = __float2bfloat16(O[dt][4 * rr + j] * inv);
                pk4[j] = *reinterpret_cast<short*>(&tb);
            }
            *(s16x4*)(ob + 32 * dt + 8 * rr + 4 * hi1) = pk4;
        }
    }
}

extern "C" void kernel_launch(void* const* d_in, const int* in_sizes, int n_in,
                              void* d_out, int out_size, void* d_ws, size_t ws_size,
                              hipStream_t stream) {
    const float* x      = (const float*)d_in[0];
    const float* w_norm = (const float*)d_in[1];
    const float* w_qkv  = (const float*)d_in[2];
    const float* w_out  = (const float*)d_in[3];

    char* ws = (char*)d_ws;
    __hip_bfloat16* xn   = (__hip_bfloat16*)(ws);                        //  8 MiB
    __hip_bfloat16* wq   = (__hip_bfloat16*)(ws + (8u  << 20));          //  6 MiB
    __hip_bfloat16* wo   = (__hip_bfloat16*)(ws + (14u << 20));          //  2 MiB
    __hip_bfloat16* qkv  = (__hip_bfloat16*)(ws + (16u << 20));          // 24 MiB (q,k used)
    __hip_bfloat16* attn = (__hip_bfloat16*)(ws + (40u << 20));          //  8 MiB
    __hip_bfloat16* vT   = (__hip_bfloat16*)(ws + (48u << 20));          //  8 MiB
    float* out = (float*)d_out;

    // fused weight conversion + RMSNorm
    prep_kernel<<<4096 + M_ROWS / 4, 256, 0, stream>>>(x, w_norm, w_qkv, w_out, xn, wq, wo);

    // QKV GEMM: [4096,1024] x [3072,1024]^T -> q,k bf16 + vT transposed (256^2, T3+T4)
    gemm_qkv_kernel<<<dim3(QKV_N / 256, M_ROWS / 256), 512, 0, stream>>>(
        xn, wq, qkv, vT, M_ROWS, QKV_N, D_);

    // MFMA banded attention -> bf16 [4096,1024]
    attn_mfma_kernel<<<dim3(L_ / 64, H_, B_), 128, 0, stream>>>(qkv, vT, attn);

    // out proj + residual: [4096,1024] x [1024,1024]^T + x -> f32 d_out
    gemm_proj_kernel<<<dim3(D_ / 64, M_ROWS / 128), 256, 0, stream>>>(
        attn, wo, out, x, M_ROWS, D_, D_);
}